// Round 2
// baseline (1312.914 us; speedup 1.0000x reference)
//
#include <hip/hip_runtime.h>

#define NN 768
#define IN_F 68
#define KNN 8
#define EO 32
#define FEAT 264
#define HALF_FEAT 132
#define EMB 32
#define NPAIR 294528   // 768*767/2

#define NBLK 1538      // (NN+1)*2 blocks in fused kernel
#define L1N 32         // level-1 arrival counters
#define FLAGN 16       // release flag copies

typedef __attribute__((ext_vector_type(8))) short bf16x8;
typedef __attribute__((ext_vector_type(4))) float f32x4;

// pack hi16(x1):hi16(x0) into one dword — bf16 truncation of two floats, 1 v_perm
static __device__ __forceinline__ int pack_chop2(float x0, float x1) {
  return __builtin_amdgcn_perm(__float_as_uint(x1), __float_as_uint(x0), 0x07060302);
}
static __device__ __forceinline__ float chop(float x) {
  return __uint_as_float(__float_as_uint(x) & 0xffff0000u);
}

// ---------------- custom lightweight grid barrier ----------------
// cg::grid_group::sync() measured ~230us/barrier at 1538 blocks (r1).
// This replaces it: hierarchical arrival (32 padded counters -> master),
// 16 padded release-flag copies, s_sleep backoff, agent-scope atomics.
// State in zero-initialized __device__ globals (workspace is re-poisoned
// by the harness every iteration; module globals are not). Monotonic
// per-phase targets; phase-4 arrival (no spin) self-resets to zero for
// the next launch / graph replay.
struct alignas(128) PadU { unsigned v; unsigned pad[31]; };
__device__ PadU g_cnt[L1N];     // zero-init (.bss)
__device__ PadU g_master;
__device__ PadU g_flag[FLAGN];

static __device__ __forceinline__ unsigned l1_expected(int c) {
  // 1538 = 32*48 + 2  ->  counters 0,1 see 49 arrivals/phase, rest 48
  return 48u + (c < 2 ? 1u : 0u);
}

static __device__ __forceinline__ void grid_barrier(int lid, unsigned phase) {
  __syncthreads();
  __threadfence();   // make prior global writes visible device-wide
  if (threadIdx.x == 0) {
    const int c = lid & (L1N - 1);
    unsigned old = __hip_atomic_fetch_add(&g_cnt[c].v, 1u,
                     __ATOMIC_ACQ_REL, __HIP_MEMORY_SCOPE_AGENT);
    if (old == phase * l1_expected(c) - 1u) {
      unsigned om = __hip_atomic_fetch_add(&g_master.v, 1u,
                      __ATOMIC_ACQ_REL, __HIP_MEMORY_SCOPE_AGENT);
      if (om == phase * L1N - 1u) {
#pragma unroll
        for (int j = 0; j < FLAGN; j++)
          __hip_atomic_store(&g_flag[j].v, phase,
                             __ATOMIC_RELEASE, __HIP_MEMORY_SCOPE_AGENT);
      }
    }
    unsigned tries = 0;
    while (__hip_atomic_load(&g_flag[lid & (FLAGN - 1)].v,
                             __ATOMIC_ACQUIRE, __HIP_MEMORY_SCOPE_AGENT) < phase) {
      __builtin_amdgcn_s_sleep(16);
      if (++tries > 4000000u) break;   // safety: fail loud (wrong result), never hang
    }
  }
  __syncthreads();
  __threadfence();   // acquire side
}

static __device__ __forceinline__ void grid_exit_reset(int lid) {
  // 4th arrival round, no spin: the unique master-completer resets all
  // state after every block has arrived (i.e. finished all flag reads).
  __threadfence();
  if (threadIdx.x == 0) {
    const int c = lid & (L1N - 1);
    unsigned old = __hip_atomic_fetch_add(&g_cnt[c].v, 1u,
                     __ATOMIC_ACQ_REL, __HIP_MEMORY_SCOPE_AGENT);
    if (old == 4u * l1_expected(c) - 1u) {
      unsigned om = __hip_atomic_fetch_add(&g_master.v, 1u,
                      __ATOMIC_ACQ_REL, __HIP_MEMORY_SCOPE_AGENT);
      if (om == 4u * L1N - 1u) {
#pragma unroll
        for (int j = 0; j < L1N; j++)
          __hip_atomic_store(&g_cnt[j].v, 0u,
                             __ATOMIC_RELAXED, __HIP_MEMORY_SCOPE_AGENT);
        __hip_atomic_store(&g_master.v, 0u,
                           __ATOMIC_RELAXED, __HIP_MEMORY_SCOPE_AGENT);
#pragma unroll
        for (int j = 0; j < FLAGN; j++)
          __hip_atomic_store(&g_flag[j].v, 0u,
                             __ATOMIC_RELAXED, __HIP_MEMORY_SCOPE_AGENT);
        __threadfence();  // end-of-kernel flush also covers this
      }
    }
  }
}

// =====================================================================
// Fused kernel: phases A (topk+ec1) / B (ec2) / C (BN stats) / D (u,v,c0)
// Grid (769,2) x 64 threads = 1538 one-wave blocks, ~7KB LDS ->
// trivially co-resident (LDS cap ~22 blocks/CU, need 6.01).
// =====================================================================
__global__ void __launch_bounds__(64) fused_abcd_kernel(
    const float* __restrict__ feat0, const float* __restrict__ feat1,
    const float* __restrict__ ec1_w1, const float* __restrict__ ec1_b1,
    const float* __restrict__ ec1_w2, const float* __restrict__ ec1_b2,
    const float* __restrict__ ec2_w1, const float* __restrict__ ec2_b1,
    const float* __restrict__ ec2_w2, const float* __restrict__ ec2_b2,
    const float* __restrict__ bn_g, const float* __restrict__ bn_b,
    const float* __restrict__ lin1_w, const float* __restrict__ lin1_b,
    int* idx, float* e1, float* e2,
    float* mu, float* sg,
    float* u, float* v, float* c0g)
{
  const int i = blockIdx.x;     // 0..768
  const int g = blockIdx.y;     // 0..1
  const int lane = threadIdx.x;
  const int lid = g*(NN+1) + i; // linear block id for barrier

  __shared__ unsigned long long keys[64*8];
  __shared__ int nbr[8];
  __shared__ float gl[KNN*IN_F];   // phase A: 8x68; phase B reuses as 8x32
  __shared__ float hsh[EO];
  __shared__ float xsh[HALF_FEAT];

  // ---------------- phase A: top-8 neighbors + EdgeConv1 ----------------
  if (i < NN) {
    const float* __restrict__ feat = g ? feat1 : feat0;
    const float4 ci = *(const float4*)(feat + i*IN_F);

    float4 cand[12];
#pragma unroll
    for (int t = 0; t < 12; t++)
      cand[t] = *(const float4*)(feat + (lane + 64*t)*IN_F);

    float bd[8]; int bidx[8];
#pragma unroll
    for (int k = 0; k < 8; k++) { bd[k] = 1e30f; bidx[k] = 0; }
#pragma unroll
    for (int t = 0; t < 12; t++) {
      const int j = lane + 64*t;
      float d = fabsf(ci.x - cand[t].x);   // same sequential add order as ref sum(-1)
      d += fabsf(ci.y - cand[t].y);
      d += fabsf(ci.z - cand[t].z);
      d += fabsf(ci.w - cand[t].w);
      if (d < bd[7]) {
#pragma unroll
        for (int k = 7; k >= 1; k--) {
          if (d < bd[k-1])    { bd[k] = bd[k-1]; bidx[k] = bidx[k-1]; }
          else if (d < bd[k]) { bd[k] = d;       bidx[k] = j; }
        }
        if (d < bd[0]) { bd[0] = d; bidx[0] = j; }
      }
    }
#pragma unroll
    for (int k = 0; k < 8; k++)
      keys[lane*8+k] = ((unsigned long long)__float_as_uint(bd[k]) << 32) | (unsigned)bidx[k];
    __syncthreads();
    int pos = 0;
#pragma unroll
    for (int r = 0; r < 8; r++) {
      unsigned long long mykey = keys[lane*8 + pos];
      unsigned long long mn = mykey;
#pragma unroll
      for (int s = 32; s >= 1; s >>= 1) {
        unsigned long long o = __shfl_xor(mn, s, 64);
        mn = (o < mn) ? o : mn;
      }
      if (mykey == mn) pos++;
      if (lane == 0) {
        int nb = (int)(mn & 0xffffffffull);
        nbr[r] = nb;
        idx[(g*NN+i)*8 + r] = nb;
      }
    }
    __syncthreads();

    for (int z = lane; z < KNN*17; z += 64) {
      int k = z / 17, q = z - k*17;
      *(float4*)&gl[k*IN_F + q*4] = *(const float4*)(feat + nbr[k]*IN_F + q*4);
    }
    __syncthreads();

    // layer1, 8 independent accumulator chains (k-major) for ILP
    const int e = lane & 31, hf = lane >> 5;
    float ak[8];
#pragma unroll
    for (int k = 0; k < 8; k++) ak[k] = 0.f;
    const int cbeg = hf*34;
    for (int c = cbeg; c < cbeg+34; c++) {
#pragma unroll
      for (int k = 0; k < 8; k++)
        ak[k] += gl[k*IN_F+c] * ec1_w1[(c*8+k)*EO + e];
    }
    float acc = ((ak[0]+ak[1])+(ak[2]+ak[3])) + ((ak[4]+ak[5])+(ak[6]+ak[7]));
    acc += __shfl_xor(acc, 32, 64);
    if (hf == 0) {
      float h = acc + ec1_b1[e];
      hsh[e] = fmaxf(h, 0.01f*h);
    }
    __syncthreads();
    if (lane < 32) {
      float o0=0.f, o1=0.f, o2=0.f, o3=0.f;
#pragma unroll
      for (int m = 0; m < 32; m += 4) {
        o0 += hsh[m+0] * ec1_w2[(m+0)*EO + lane];
        o1 += hsh[m+1] * ec1_w2[(m+1)*EO + lane];
        o2 += hsh[m+2] * ec1_w2[(m+2)*EO + lane];
        o3 += hsh[m+3] * ec1_w2[(m+3)*EO + lane];
      }
      float o = ec1_b2[lane] + ((o0+o1)+(o2+o3));
      o = fmaxf(o, 0.01f*o);
      e1[(g*NN+i)*EO + lane] = o;
    }
  }
  grid_barrier(lid, 1);

  // ---------------- phase B: EdgeConv2 ----------------
  if (i < NN) {
    {
      const int k = lane >> 3, q = lane & 7;
      const int nb = idx[(g*NN+i)*8 + k];
      *(float4*)&gl[k*EO + q*4] = *(const float4*)(e1 + (g*NN+nb)*EO + q*4);
    }
    __syncthreads();
    const int e = lane & 31, hf = lane >> 5;
    float ak[8];
#pragma unroll
    for (int k = 0; k < 8; k++) ak[k] = 0.f;
    const int cbeg = hf*16;
    for (int c = cbeg; c < cbeg+16; c++) {
#pragma unroll
      for (int k = 0; k < 8; k++)
        ak[k] += gl[k*EO+c] * ec2_w1[(c*8+k)*EO + e];
    }
    float acc = ((ak[0]+ak[1])+(ak[2]+ak[3])) + ((ak[4]+ak[5])+(ak[6]+ak[7]));
    acc += __shfl_xor(acc, 32, 64);
    if (hf == 0) {
      float h = acc + ec2_b1[e];
      hsh[e] = fmaxf(h, 0.01f*h);
    }
    __syncthreads();
    if (lane < 32) {
      float o0=0.f, o1=0.f, o2=0.f, o3=0.f;
#pragma unroll
      for (int m = 0; m < 32; m += 4) {
        o0 += hsh[m+0] * ec2_w2[(m+0)*EO + lane];
        o1 += hsh[m+1] * ec2_w2[(m+1)*EO + lane];
        o2 += hsh[m+2] * ec2_w2[(m+2)*EO + lane];
        o3 += hsh[m+3] * ec2_w2[(m+3)*EO + lane];
      }
      float o = ec2_b2[lane] + ((o0+o1)+(o2+o3));
      o = fmaxf(o, 0.01f*o);
      e2[(g*NN+i)*EO + lane] = o;
    }
  }
  grid_barrier(lid, 2);

  // ---------------- phase C: BN stats (132 one-wave channel blocks) ----------------
  if (g == 0 && i < HALF_FEAT) {
    const int c = i;
    double s1=0, s2=0, q1=0, q2=0;
    for (int t = lane; t < 2*NN; t += 64) {
      int gg = t >= NN;
      int n = t - gg*NN;
      float val;
      if (c < IN_F)      val = (gg ? feat1 : feat0)[n*IN_F + c];
      else if (c < 100)  val = e1[(gg*NN+n)*EO + (c-IN_F)];
      else               val = e2[(gg*NN+n)*EO + (c-100)];
      double dv = val;
      double wf = (double)(NN-1-n), wsnd = (double)n;
      s1 += wf*dv;  s2 += wsnd*dv;
      double dq = dv*dv;
      q1 += wf*dq;  q2 += wsnd*dq;
    }
#pragma unroll
    for (int off = 32; off >= 1; off >>= 1) {
      s1 += __shfl_xor(s1, off, 64);
      s2 += __shfl_xor(s2, off, 64);
      q1 += __shfl_xor(q1, off, 64);
      q2 += __shfl_xor(q2, off, 64);
    }
    if (lane == 0) {
      const double M2 = 2.0 * (double)NPAIR;
      double mu1 = s1/M2, mu2 = s2/M2;
      double v1 = q1/M2 - mu1*mu1;
      double v2 = q2/M2 - mu2*mu2;
      mu[c]           = (float)mu1;
      mu[HALF_FEAT+c] = (float)mu2;
      sg[c]           = (float)((double)bn_g[c] / sqrt(v1 + 1e-5));
      sg[HALF_FEAT+c] = (float)((double)bn_g[HALF_FEAT+c] / sqrt(v2 + 1e-5));
    }
  }
  grid_barrier(lid, 3);

  // ---------------- phase D: per-node u/v, plus c0 ----------------
  if (i == NN) {
    if (g == 0 && lane < EMB) {
      float a0=0.f, a1=0.f, a2=0.f, a3=0.f;
      for (int c = 0; c < FEAT; c += 4) {
        a0 += (bn_b[c+0] - mu[c+0]*sg[c+0]) * lin1_w[(c+0)*EMB + lane];
        a1 += (bn_b[c+1] - mu[c+1]*sg[c+1]) * lin1_w[(c+1)*EMB + lane];
        a2 += (bn_b[c+2] - mu[c+2]*sg[c+2]) * lin1_w[(c+2)*EMB + lane];
        a3 += (bn_b[c+3] - mu[c+3]*sg[c+3]) * lin1_w[(c+3)*EMB + lane];
      }
      c0g[lane] = lin1_b[lane] + ((a0+a1)+(a2+a3));
    }
  } else {
    for (int c = lane; c < IN_F; c += 64) xsh[c] = (g ? feat1 : feat0)[i*IN_F + c];
    if (lane < 32) xsh[IN_F + lane]       = e1[(g*NN+i)*EO + lane];
    else           xsh[100 + (lane-32)]   = e2[(g*NN+i)*EO + (lane-32)];
    __syncthreads();
    const int e = lane & 31, hf = lane >> 5;
    const int base = hf * HALF_FEAT;
    float a0=0.f, a1=0.f, a2=0.f, a3=0.f;
    for (int c = 0; c < HALF_FEAT; c += 4) {
      a0 += xsh[c+0] * sg[base+c+0] * lin1_w[(base+c+0)*EMB + e];
      a1 += xsh[c+1] * sg[base+c+1] * lin1_w[(base+c+1)*EMB + e];
      a2 += xsh[c+2] * sg[base+c+2] * lin1_w[(base+c+2)*EMB + e];
      a3 += xsh[c+3] * sg[base+c+3] * lin1_w[(base+c+3)*EMB + e];
    }
    float acc = ((a0+a1)+(a2+a3));
    float* dst = hf ? v : u;
    dst[(g*NN+i)*EMB + e] = acc;
  }
  grid_exit_reset(lid);
}

// =====================================================================
// Fallback path (only used if cooperative launch is rejected at enqueue)
// =====================================================================
__global__ void __launch_bounds__(64) topk_ec1_kernel(
    const float* __restrict__ feat0, const float* __restrict__ feat1,
    const float* __restrict__ w1, const float* __restrict__ b1,
    const float* __restrict__ w2, const float* __restrict__ b2,
    int* __restrict__ idx_out, float* __restrict__ e1out)
{
  const int i = blockIdx.x, g = blockIdx.y;
  const float* __restrict__ feat = g ? feat1 : feat0;
  const int lane = threadIdx.x;

  __shared__ unsigned long long keys[64*8];
  __shared__ int nbr[8];
  __shared__ float gl[KNN*IN_F];
  __shared__ float hsh[EO];

  const float4 ci = *(const float4*)(feat + i*IN_F);

  float4 cand[12];
#pragma unroll
  for (int t = 0; t < 12; t++)
    cand[t] = *(const float4*)(feat + (lane + 64*t)*IN_F);

  float bd[8]; int bidx[8];
#pragma unroll
  for (int k = 0; k < 8; k++) { bd[k] = 1e30f; bidx[k] = 0; }
#pragma unroll
  for (int t = 0; t < 12; t++) {
    const int j = lane + 64*t;
    float d = fabsf(ci.x - cand[t].x);
    d += fabsf(ci.y - cand[t].y);
    d += fabsf(ci.z - cand[t].z);
    d += fabsf(ci.w - cand[t].w);
    if (d < bd[7]) {
#pragma unroll
      for (int k = 7; k >= 1; k--) {
        if (d < bd[k-1])    { bd[k] = bd[k-1]; bidx[k] = bidx[k-1]; }
        else if (d < bd[k]) { bd[k] = d;       bidx[k] = j; }
      }
      if (d < bd[0]) { bd[0] = d; bidx[0] = j; }
    }
  }
#pragma unroll
  for (int k = 0; k < 8; k++)
    keys[lane*8+k] = ((unsigned long long)__float_as_uint(bd[k]) << 32) | (unsigned)bidx[k];
  __syncthreads();
  int pos = 0;
#pragma unroll
  for (int r = 0; r < 8; r++) {
    unsigned long long mykey = keys[lane*8 + pos];
    unsigned long long mn = mykey;
#pragma unroll
    for (int s = 32; s >= 1; s >>= 1) {
      unsigned long long o = __shfl_xor(mn, s, 64);
      mn = (o < mn) ? o : mn;
    }
    if (mykey == mn) pos++;
    if (lane == 0) {
      int nb = (int)(mn & 0xffffffffull);
      nbr[r] = nb;
      idx_out[(g*NN+i)*8 + r] = nb;
    }
  }
  __syncthreads();

  for (int z = lane; z < KNN*17; z += 64) {
    int k = z / 17, q = z - k*17;
    *(float4*)&gl[k*IN_F + q*4] = *(const float4*)(feat + nbr[k]*IN_F + q*4);
  }
  __syncthreads();

  const int e = lane & 31, hf = lane >> 5;
  float ak[8];
#pragma unroll
  for (int k = 0; k < 8; k++) ak[k] = 0.f;
  const int cbeg = hf*34;
  for (int c = cbeg; c < cbeg+34; c++) {
#pragma unroll
    for (int k = 0; k < 8; k++)
      ak[k] += gl[k*IN_F+c] * w1[(c*8+k)*EO + e];
  }
  float acc = ((ak[0]+ak[1])+(ak[2]+ak[3])) + ((ak[4]+ak[5])+(ak[6]+ak[7]));
  acc += __shfl_xor(acc, 32, 64);
  if (hf == 0) {
    float h = acc + b1[e];
    hsh[e] = fmaxf(h, 0.01f*h);
  }
  __syncthreads();
  if (lane < 32) {
    float o0=0.f, o1=0.f, o2=0.f, o3=0.f;
#pragma unroll
    for (int m = 0; m < 32; m += 4) {
      o0 += hsh[m+0] * w2[(m+0)*EO + lane];
      o1 += hsh[m+1] * w2[(m+1)*EO + lane];
      o2 += hsh[m+2] * w2[(m+2)*EO + lane];
      o3 += hsh[m+3] * w2[(m+3)*EO + lane];
    }
    float o = b2[lane] + ((o0+o1)+(o2+o3));
    o = fmaxf(o, 0.01f*o);
    e1out[(g*NN+i)*EO + lane] = o;
  }
}

__global__ void __launch_bounds__(64) ec2_kernel(
    const int* __restrict__ idx, const float* __restrict__ e1,
    const float* __restrict__ w1, const float* __restrict__ b1,
    const float* __restrict__ w2, const float* __restrict__ b2,
    float* __restrict__ e2out)
{
  const int i = blockIdx.x, g = blockIdx.y;
  const int lane = threadIdx.x;
  __shared__ float gl[KNN*EO];
  __shared__ float hsh[EO];
  {
    const int k = lane >> 3, q = lane & 7;
    const int nb = idx[(g*NN+i)*8 + k];
    *(float4*)&gl[k*EO + q*4] = *(const float4*)(e1 + (g*NN+nb)*EO + q*4);
  }
  __syncthreads();
  const int e = lane & 31, hf = lane >> 5;
  float ak[8];
#pragma unroll
  for (int k = 0; k < 8; k++) ak[k] = 0.f;
  const int cbeg = hf*16;
  for (int c = cbeg; c < cbeg+16; c++) {
#pragma unroll
    for (int k = 0; k < 8; k++)
      ak[k] += gl[k*EO+c] * w1[(c*8+k)*EO + e];
  }
  float acc = ((ak[0]+ak[1])+(ak[2]+ak[3])) + ((ak[4]+ak[5])+(ak[6]+ak[7]));
  acc += __shfl_xor(acc, 32, 64);
  if (hf == 0) {
    float h = acc + b1[e];
    hsh[e] = fmaxf(h, 0.01f*h);
  }
  __syncthreads();
  if (lane < 32) {
    float o0=0.f, o1=0.f, o2=0.f, o3=0.f;
#pragma unroll
    for (int m = 0; m < 32; m += 4) {
      o0 += hsh[m+0] * w2[(m+0)*EO + lane];
      o1 += hsh[m+1] * w2[(m+1)*EO + lane];
      o2 += hsh[m+2] * w2[(m+2)*EO + lane];
      o3 += hsh[m+3] * w2[(m+3)*EO + lane];
    }
    float o = b2[lane] + ((o0+o1)+(o2+o3));
    o = fmaxf(o, 0.01f*o);
    e2out[(g*NN+i)*EO + lane] = o;
  }
}

__global__ void __launch_bounds__(256) stats_kernel(
    const float* __restrict__ feat0, const float* __restrict__ feat1,
    const float* __restrict__ e1, const float* __restrict__ e2,
    const float* __restrict__ bn_g,
    float* __restrict__ mu_out, float* __restrict__ sg_out)
{
  const int c = blockIdx.x;
  const int tid = threadIdx.x;
  double s1=0, s2=0, q1=0, q2=0;
  for (int t = tid; t < 2*NN; t += 256) {
    int g = t >= NN;
    int i = t - g*NN;
    float val;
    if (c < IN_F)      val = (g ? feat1 : feat0)[i*IN_F + c];
    else if (c < 100)  val = e1[(g*NN+i)*EO + (c-IN_F)];
    else               val = e2[(g*NN+i)*EO + (c-100)];
    double dv = val;
    double wf = (double)(NN-1-i), wsnd = (double)i;
    s1 += wf*dv;  s2 += wsnd*dv;
    double dq = dv*dv;
    q1 += wf*dq;  q2 += wsnd*dq;
  }
#pragma unroll
  for (int off = 32; off >= 1; off >>= 1) {
    s1 += __shfl_xor(s1, off, 64);
    s2 += __shfl_xor(s2, off, 64);
    q1 += __shfl_xor(q1, off, 64);
    q2 += __shfl_xor(q2, off, 64);
  }
  __shared__ double red[4][4];
  const int w = tid >> 6;
  if ((tid & 63) == 0) { red[w][0]=s1; red[w][1]=s2; red[w][2]=q1; red[w][3]=q2; }
  __syncthreads();
  if (tid == 0) {
    double t0 = red[0][0]+red[1][0]+red[2][0]+red[3][0];
    double t1 = red[0][1]+red[1][1]+red[2][1]+red[3][1];
    double t2 = red[0][2]+red[1][2]+red[2][2]+red[3][2];
    double t3 = red[0][3]+red[1][3]+red[2][3]+red[3][3];
    const double M2 = 2.0 * (double)NPAIR;
    double mu1 = t0/M2, mu2 = t1/M2;
    double v1 = t2/M2 - mu1*mu1;
    double v2 = t3/M2 - mu2*mu2;
    mu_out[c]           = (float)mu1;
    mu_out[HALF_FEAT+c] = (float)mu2;
    sg_out[c]           = (float)((double)bn_g[c] / sqrt(v1 + 1e-5));
    sg_out[HALF_FEAT+c] = (float)((double)bn_g[HALF_FEAT+c] / sqrt(v2 + 1e-5));
  }
}

__global__ void __launch_bounds__(64) uv_c0_kernel(
    const float* __restrict__ feat0, const float* __restrict__ feat1,
    const float* __restrict__ e1, const float* __restrict__ e2,
    const float* __restrict__ sg, const float* __restrict__ mu,
    const float* __restrict__ bn_b,
    const float* __restrict__ lin1_w, const float* __restrict__ lin1_b,
    float* __restrict__ u, float* __restrict__ v, float* __restrict__ c0g)
{
  const int i = blockIdx.x, g = blockIdx.y;
  const int t = threadIdx.x;
  if (i == NN) {
    if (g == 0 && t < EMB) {
      float a0=0.f, a1=0.f, a2=0.f, a3=0.f;
      for (int c = 0; c < FEAT; c += 4) {
        a0 += (bn_b[c+0] - mu[c+0]*sg[c+0]) * lin1_w[(c+0)*EMB + t];
        a1 += (bn_b[c+1] - mu[c+1]*sg[c+1]) * lin1_w[(c+1)*EMB + t];
        a2 += (bn_b[c+2] - mu[c+2]*sg[c+2]) * lin1_w[(c+2)*EMB + t];
        a3 += (bn_b[c+3] - mu[c+3]*sg[c+3]) * lin1_w[(c+3)*EMB + t];
      }
      c0g[t] = lin1_b[t] + ((a0+a1)+(a2+a3));
    }
    return;
  }
  __shared__ float x[HALF_FEAT];
  for (int c = t; c < IN_F; c += 64) x[c] = (g ? feat1 : feat0)[i*IN_F + c];
  if (t < 32) x[IN_F + t]     = e1[(g*NN+i)*EO + t];
  else        x[100 + (t-32)] = e2[(g*NN+i)*EO + (t-32)];
  __syncthreads();
  const int e = t & 31, hf = t >> 5;
  const int base = hf * HALF_FEAT;
  float a0=0.f, a1=0.f, a2=0.f, a3=0.f;
  for (int c = 0; c < HALF_FEAT; c += 4) {
    a0 += x[c+0] * sg[base+c+0] * lin1_w[(base+c+0)*EMB + e];
    a1 += x[c+1] * sg[base+c+1] * lin1_w[(base+c+1)*EMB + e];
    a2 += x[c+2] * sg[base+c+2] * lin1_w[(base+c+2)*EMB + e];
    a3 += x[c+3] * sg[base+c+3] * lin1_w[(base+c+3)*EMB + e];
  }
  float acc = ((a0+a1)+(a2+a3));
  float* dst = hf ? v : u;
  dst[(g*NN+i)*EMB + e] = acc;
}

// ---------------- Kernel E: pair MLP via split-bf16 MFMA (unchanged) ----------------
__global__ void __launch_bounds__(256) pair_kernel(
    const float* __restrict__ u, const float* __restrict__ v,
    const float* __restrict__ c0g,
    const float* __restrict__ lin2_w, const float* __restrict__ lin2_b,
    const float* __restrict__ lin3_w, const float* __restrict__ lin3_b,
    float2* __restrict__ out)
{
  const int g = blockIdx.y;
  int rem = blockIdx.x;        // 0..1175 triangular tile id
  int a = 0;
  while (rem >= 48 - a) { rem -= 48 - a; a++; }
  const int b = a + rem;

  __shared__ float su[16*36], sv[16*36];
  __shared__ float wbuf[4][16*36];
  const int tid = threadIdx.x;
  {
    int r = tid >> 5, c = tid & 31;
    su[r*36+c] = u[(g*NN + a*16 + r)*EMB + c];
    sv[r*36+c] = v[(g*NN + b*16 + r)*EMB + c];
    r += 8;
    su[r*36+c] = u[(g*NN + a*16 + r)*EMB + c];
    sv[r*36+c] = v[(g*NN + b*16 + r)*EMB + c];
  }
  __syncthreads();

  const int lane = tid & 63, w = tid >> 6;
  const int q = lane & 15, kg = lane >> 4;   // q: m/n index, kg: k-group

  union { int i[4]; bf16x8 v; } whi0, wlo0, whi1, wlo1;
#pragma unroll
  for (int d = 0; d < 4; d++) {
    float w0a = lin2_w[(kg*8+2*d)*32 + q];
    float w0b = lin2_w[(kg*8+2*d+1)*32 + q];
    float w1a = lin2_w[(kg*8+2*d)*32 + 16 + q];
    float w1b = lin2_w[(kg*8+2*d+1)*32 + 16 + q];
    whi0.i[d] = pack_chop2(w0a, w0b);
    wlo0.i[d] = pack_chop2(w0a - chop(w0a), w0b - chop(w0b));
    whi1.i[d] = pack_chop2(w1a, w1b);
    wlo1.i[d] = pack_chop2(w1a - chop(w1a), w1b - chop(w1b));
  }
  float svc[8];
#pragma unroll
  for (int jj = 0; jj < 8; jj++)
    svc[jj] = sv[q*36 + kg*8 + jj] + c0g[kg*8+jj];
  float2 w3v[8]; float b2v[8];
#pragma unroll
  for (int jj = 0; jj < 8; jj++) {
    w3v[jj] = ((const float2*)lin3_w)[kg*8+jj];
    b2v[jj] = lin2_b[kg*8+jj];
  }
  const float b30 = lin3_b[0], b31 = lin3_b[1];

  float* wb = wbuf[w];
#pragma unroll
  for (int t = 0; t < 4; t++) {
    const int ty = w*4 + t;
    const float4 sa = *(const float4*)&su[ty*36 + kg*8];
    const float4 sb = *(const float4*)&su[ty*36 + kg*8 + 4];
    float se[8] = {sa.x, sa.y, sa.z, sa.w, sb.x, sb.y, sb.z, sb.w};
    union { int i[4]; bf16x8 v; } ahi, alo;
#pragma unroll
    for (int d = 0; d < 4; d++) {
      float s0 = se[2*d]   + svc[2*d];
      float s1 = se[2*d+1] + svc[2*d+1];
      s0 = fmaxf(s0, 0.01f*s0);
      s1 = fmaxf(s1, 0.01f*s1);
      ahi.i[d] = pack_chop2(s0, s1);
      alo.i[d] = pack_chop2(s0 - chop(s0), s1 - chop(s1));
    }
    f32x4 acc0 = {0.f,0.f,0.f,0.f}, acc1 = {0.f,0.f,0.f,0.f};
    acc0 = __builtin_amdgcn_mfma_f32_16x16x32_bf16(ahi.v, whi0.v, acc0, 0,0,0);
    acc1 = __builtin_amdgcn_mfma_f32_16x16x32_bf16(ahi.v, whi1.v, acc1, 0,0,0);
    acc0 = __builtin_amdgcn_mfma_f32_16x16x32_bf16(ahi.v, wlo0.v, acc0, 0,0,0);
    acc1 = __builtin_amdgcn_mfma_f32_16x16x32_bf16(ahi.v, wlo1.v, acc1, 0,0,0);
    acc0 = __builtin_amdgcn_mfma_f32_16x16x32_bf16(alo.v, whi0.v, acc0, 0,0,0);
    acc1 = __builtin_amdgcn_mfma_f32_16x16x32_bf16(alo.v, whi1.v, acc1, 0,0,0);
#pragma unroll
    for (int r = 0; r < 4; r++) {
      wb[(kg*4+r)*36 + q]      = acc0[r];
      wb[(kg*4+r)*36 + 16 + q] = acc1[r];
    }
    float o0 = 0.f, o1 = 0.f;
#pragma unroll
    for (int jj = 0; jj < 8; jj++) {
      float h = wb[q*36 + kg*8 + jj] + b2v[jj];
      h = fmaxf(h, 0.01f*h);
      o0 += h * w3v[jj].x;
      o1 += h * w3v[jj].y;
    }
    o0 += __shfl_xor(o0, 16, 64); o0 += __shfl_xor(o0, 32, 64);
    o1 += __shfl_xor(o1, 16, 64); o1 += __shfl_xor(o1, 32, 64);
    const int i = a*16 + ty, j = b*16 + q;
    if (lane < 16 && j > i) {
      long p = (long)i*NN - (long)i*(i+1)/2 + (j - i - 1);
      out[(long)g*NPAIR + p] = make_float2(o0 + b30, o1 + b31);
    }
  }
}

extern "C" void kernel_launch(void* const* d_in, const int* in_sizes, int n_in,
                              void* d_out, int out_size, void* d_ws, size_t ws_size,
                              hipStream_t stream)
{
  const float* feat0  = (const float*)d_in[0];
  const float* feat1  = (const float*)d_in[1];
  const float* ec1_w1 = (const float*)d_in[2];
  const float* ec1_b1 = (const float*)d_in[3];
  const float* ec1_w2 = (const float*)d_in[4];
  const float* ec1_b2 = (const float*)d_in[5];
  const float* ec2_w1 = (const float*)d_in[6];
  const float* ec2_b1 = (const float*)d_in[7];
  const float* ec2_w2 = (const float*)d_in[8];
  const float* ec2_b2 = (const float*)d_in[9];
  const float* bn_g   = (const float*)d_in[10];
  const float* bn_b   = (const float*)d_in[11];
  const float* lin1_w = (const float*)d_in[12];
  const float* lin1_b = (const float*)d_in[13];
  const float* lin2_w = (const float*)d_in[14];
  const float* lin2_b = (const float*)d_in[15];
  const float* lin3_w = (const float*)d_in[16];
  const float* lin3_b = (const float*)d_in[17];

  char* ws = (char*)d_ws;
  int*   idx = (int*)  (ws + 0);
  float* e1  = (float*)(ws + 49152);
  float* e2  = (float*)(ws + 245760);
  float* u   = (float*)(ws + 442368);
  float* v   = (float*)(ws + 638976);
  float* mu  = (float*)(ws + 835584);
  float* sg  = (float*)(ws + 836640);
  float* c0g = (float*)(ws + 837696);

  void* kargs[] = {
    (void*)&feat0, (void*)&feat1,
    (void*)&ec1_w1, (void*)&ec1_b1, (void*)&ec1_w2, (void*)&ec1_b2,
    (void*)&ec2_w1, (void*)&ec2_b1, (void*)&ec2_w2, (void*)&ec2_b2,
    (void*)&bn_g, (void*)&bn_b, (void*)&lin1_w, (void*)&lin1_b,
    (void*)&idx, (void*)&e1, (void*)&e2,
    (void*)&mu, (void*)&sg, (void*)&u, (void*)&v, (void*)&c0g
  };
  hipError_t cerr = hipLaunchCooperativeKernel(
      (const void*)fused_abcd_kernel, dim3(NN+1, 2), dim3(64, 1, 1),
      kargs, 0, stream);
  if (cerr != hipSuccess) {
    // fallback: original 4-kernel chain
    topk_ec1_kernel<<<dim3(768,2), 64, 0, stream>>>(feat0, feat1, ec1_w1, ec1_b1,
                                                    ec1_w2, ec1_b2, idx, e1);
    ec2_kernel<<<dim3(768,2), 64, 0, stream>>>(idx, e1, ec2_w1, ec2_b1,
                                               ec2_w2, ec2_b2, e2);
    stats_kernel<<<dim3(132), 256, 0, stream>>>(feat0, feat1, e1, e2, bn_g, mu, sg);
    uv_c0_kernel<<<dim3(769,2), 64, 0, stream>>>(feat0, feat1, e1, e2, sg, mu, bn_b,
                                                 lin1_w, lin1_b, u, v, c0g);
  }
  pair_kernel<<<dim3(1176,2), 256, 0, stream>>>(u, v, c0g, lin2_w, lin2_b,
                                                lin3_w, lin3_b, (float2*)d_out);
}

// Round 4
// 240.625 us; speedup vs baseline: 5.4563x; 5.4563x over previous
//
#include <hip/hip_runtime.h>

#define NN 768
#define IN_F 68
#define KNN 8
#define EO 32
#define FEAT 264
#define HALF_FEAT 132
#define EMB 32
#define NPAIR 294528   // 768*767/2

typedef __attribute__((ext_vector_type(8))) short bf16x8;
typedef __attribute__((ext_vector_type(4))) float f32x4;

// pack hi16(x1):hi16(x0) into one dword — bf16 truncation of two floats, 1 v_perm
static __device__ __forceinline__ int pack_chop2(float x0, float x1) {
  return __builtin_amdgcn_perm(__float_as_uint(x1), __float_as_uint(x0), 0x07060302);
}
static __device__ __forceinline__ float chop(float x) {
  return __uint_as_float(__float_as_uint(x) & 0xffff0000u);
}

// ---------------- fixed-point BN-stat accumulators ----------------
// Grid-wide barriers cost 230-400us on MI355X (r1/r2: per-block device-scope
// fences -> whole-L2 writeback/invalidate). So stats are accumulated with
// RELAXED agent-scope integer atomics (performed at the coherent point; NO
// fences anywhere). Weighted sums decompose: s1 = 767*T0 - T1 with
// T0 = sum(v), T1 = sum(i*v) -- integer-exact, order-independent.
// Quantization: linear 2^24, squares 2^16 -> mu/var error ~1e-8..1e-6.
// Accumulators in zero-init .bss; the unique last B-block finalizes and
// resets them to zero for the next graph replay (invariant: zero at chain
// start of every iteration).
#define SL 16777216.0   // 2^24
#define SQ 65536.0      // 2^16

__device__ long long g_T0[HALF_FEAT];   // sum v
__device__ long long g_T1[HALF_FEAT];   // sum i*v
__device__ long long g_Q0[HALF_FEAT];   // sum v^2
__device__ long long g_Q1[HALF_FEAT];   // sum i*v^2
__device__ unsigned  g_done;

static __device__ __forceinline__ void stat_add(int c, int i, float v) {
  long long iq = __double2ll_rn((double)v * SL);
  long long qq = __double2ll_rn((double)v * (double)v * SQ);
  __hip_atomic_fetch_add(&g_T0[c], iq, __ATOMIC_RELAXED, __HIP_MEMORY_SCOPE_AGENT);
  __hip_atomic_fetch_add(&g_T1[c], (long long)i * iq, __ATOMIC_RELAXED, __HIP_MEMORY_SCOPE_AGENT);
  __hip_atomic_fetch_add(&g_Q0[c], qq, __ATOMIC_RELAXED, __HIP_MEMORY_SCOPE_AGENT);
  __hip_atomic_fetch_add(&g_Q1[c], (long long)i * qq, __ATOMIC_RELAXED, __HIP_MEMORY_SCOPE_AGENT);
}

// ---------------- Kernel A: top-8 neighbors + EdgeConv1 + feat/e1 stats ----
__global__ void __launch_bounds__(64) topk_ec1_kernel(
    const float* __restrict__ feat0, const float* __restrict__ feat1,
    const float* __restrict__ w1, const float* __restrict__ b1,
    const float* __restrict__ w2, const float* __restrict__ b2,
    int* __restrict__ idx_out, float* __restrict__ e1out)
{
  const int i = blockIdx.x, g = blockIdx.y;
  const float* __restrict__ feat = g ? feat1 : feat0;
  const int lane = threadIdx.x;

  __shared__ unsigned long long keys[64*8];
  __shared__ int nbr[8];
  __shared__ float gl[KNN*IN_F];
  __shared__ float hsh[EO];

  const float4 ci = *(const float4*)(feat + i*IN_F);

  float4 cand[12];
#pragma unroll
  for (int t = 0; t < 12; t++)
    cand[t] = *(const float4*)(feat + (lane + 64*t)*IN_F);

  float bd[8]; int bidx[8];
#pragma unroll
  for (int k = 0; k < 8; k++) { bd[k] = 1e30f; bidx[k] = 0; }
#pragma unroll
  for (int t = 0; t < 12; t++) {
    const int j = lane + 64*t;
    float d = fabsf(ci.x - cand[t].x);   // same sequential add order as ref sum(-1)
    d += fabsf(ci.y - cand[t].y);
    d += fabsf(ci.z - cand[t].z);
    d += fabsf(ci.w - cand[t].w);
    if (d < bd[7]) {
#pragma unroll
      for (int k = 7; k >= 1; k--) {
        if (d < bd[k-1])    { bd[k] = bd[k-1]; bidx[k] = bidx[k-1]; }
        else if (d < bd[k]) { bd[k] = d;       bidx[k] = j; }
      }
      if (d < bd[0]) { bd[0] = d; bidx[0] = j; }
    }
  }
#pragma unroll
  for (int k = 0; k < 8; k++)
    keys[lane*8+k] = ((unsigned long long)__float_as_uint(bd[k]) << 32) | (unsigned)bidx[k];
  __syncthreads();
  int pos = 0;
#pragma unroll
  for (int r = 0; r < 8; r++) {
    unsigned long long mykey = keys[lane*8 + pos];
    unsigned long long mn = mykey;
#pragma unroll
    for (int s = 32; s >= 1; s >>= 1) {
      unsigned long long o = __shfl_xor(mn, s, 64);
      mn = (o < mn) ? o : mn;
    }
    if (mykey == mn) pos++;
    if (lane == 0) {
      int nb = (int)(mn & 0xffffffffull);
      nbr[r] = nb;
      idx_out[(g*NN+i)*8 + r] = nb;
    }
  }
  __syncthreads();

  for (int z = lane; z < KNN*17; z += 64) {
    int k = z / 17, q = z - k*17;
    *(float4*)&gl[k*IN_F + q*4] = *(const float4*)(feat + nbr[k]*IN_F + q*4);
  }
  __syncthreads();

  // layer1, 8 independent accumulator chains (k-major) for ILP
  const int e = lane & 31, hf = lane >> 5;
  float ak[8];
#pragma unroll
  for (int k = 0; k < 8; k++) ak[k] = 0.f;
  const int cbeg = hf*34;
  for (int c = cbeg; c < cbeg+34; c++) {
#pragma unroll
    for (int k = 0; k < 8; k++)
      ak[k] += gl[k*IN_F+c] * w1[(c*8+k)*EO + e];
  }
  float acc = ((ak[0]+ak[1])+(ak[2]+ak[3])) + ((ak[4]+ak[5])+(ak[6]+ak[7]));
  acc += __shfl_xor(acc, 32, 64);
  if (hf == 0) {
    float h = acc + b1[e];
    hsh[e] = fmaxf(h, 0.01f*h);
  }
  __syncthreads();
  if (lane < 32) {
    float o0=0.f, o1=0.f, o2=0.f, o3=0.f;
#pragma unroll
    for (int m = 0; m < 32; m += 4) {
      o0 += hsh[m+0] * w2[(m+0)*EO + lane];
      o1 += hsh[m+1] * w2[(m+1)*EO + lane];
      o2 += hsh[m+2] * w2[(m+2)*EO + lane];
      o3 += hsh[m+3] * w2[(m+3)*EO + lane];
    }
    float o = b2[lane] + ((o0+o1)+(o2+o3));
    o = fmaxf(o, 0.01f*o);
    e1out[(g*NN+i)*EO + lane] = o;
    stat_add(IN_F + lane, i, o);          // e1 stats (channels 68..99)
  }
  // feat stats (channels 0..67), own row
  for (int z = lane; z < IN_F; z += 64)
    stat_add(z, i, feat[i*IN_F + z]);
}

// ---------------- Kernel B: EdgeConv2 + e2 stats + last-block finalize ----
__global__ void __launch_bounds__(64) ec2_kernel(
    const int* __restrict__ idx, const float* __restrict__ e1,
    const float* __restrict__ w1, const float* __restrict__ b1,
    const float* __restrict__ w2, const float* __restrict__ b2,
    const float* __restrict__ bn_g, const float* __restrict__ bn_b,
    const float* __restrict__ lin1_w, const float* __restrict__ lin1_b,
    float* __restrict__ e2out,
    float* __restrict__ mu_out, float* __restrict__ sg_out,
    float* __restrict__ c0g)
{
  const int i = blockIdx.x, g = blockIdx.y;
  const int lane = threadIdx.x;
  __shared__ float gl[KNN*EO];
  __shared__ float hsh[EO];
  __shared__ float smu[FEAT], ssg[FEAT];
  __shared__ int isLast;
  {
    const int k = lane >> 3, q = lane & 7;
    const int nb = idx[(g*NN+i)*8 + k];
    *(float4*)&gl[k*EO + q*4] = *(const float4*)(e1 + (g*NN+nb)*EO + q*4);
  }
  __syncthreads();
  const int e = lane & 31, hf = lane >> 5;
  float ak[8];
#pragma unroll
  for (int k = 0; k < 8; k++) ak[k] = 0.f;
  const int cbeg = hf*16;
  for (int c = cbeg; c < cbeg+16; c++) {
#pragma unroll
    for (int k = 0; k < 8; k++)
      ak[k] += gl[k*EO+c] * w1[(c*8+k)*EO + e];
  }
  float acc = ((ak[0]+ak[1])+(ak[2]+ak[3])) + ((ak[4]+ak[5])+(ak[6]+ak[7]));
  acc += __shfl_xor(acc, 32, 64);
  if (hf == 0) {
    float h = acc + b1[e];
    hsh[e] = fmaxf(h, 0.01f*h);
  }
  __syncthreads();
  if (lane < 32) {
    float o0=0.f, o1=0.f, o2=0.f, o3=0.f;
#pragma unroll
    for (int m = 0; m < 32; m += 4) {
      o0 += hsh[m+0] * w2[(m+0)*EO + lane];
      o1 += hsh[m+1] * w2[(m+1)*EO + lane];
      o2 += hsh[m+2] * w2[(m+2)*EO + lane];
      o3 += hsh[m+3] * w2[(m+3)*EO + lane];
    }
    float o = b2[lane] + ((o0+o1)+(o2+o3));
    o = fmaxf(o, 0.01f*o);
    e2out[(g*NN+i)*EO + lane] = o;
    stat_add(100 + lane, i, o);           // e2 stats (channels 100..131)
  }

  // ---- completion detection: single-wave block, so vmcnt(0) covers all
  // lanes' atomic issues; done-counter increment is physically after the
  // stat atomics have been performed at the coherent point. No fences.
  asm volatile("s_waitcnt vmcnt(0)" ::: "memory");
  if (lane == 0) {
    unsigned old = __hip_atomic_fetch_add(&g_done, 1u,
                     __ATOMIC_RELAXED, __HIP_MEMORY_SCOPE_AGENT);
    isLast = (old == 2u*NN - 1u);
  }
  __syncthreads();
  if (!isLast) return;

  // ---- finalize (unique last block): mu, sg, then c0g. Reads via
  // agent-scope atomic loads (coherent path), resets for next iteration.
  for (int c = lane; c < HALF_FEAT; c += 64) {
    long long T0 = __hip_atomic_load(&g_T0[c], __ATOMIC_RELAXED, __HIP_MEMORY_SCOPE_AGENT);
    long long T1 = __hip_atomic_load(&g_T1[c], __ATOMIC_RELAXED, __HIP_MEMORY_SCOPE_AGENT);
    long long Q0 = __hip_atomic_load(&g_Q0[c], __ATOMIC_RELAXED, __HIP_MEMORY_SCOPE_AGENT);
    long long Q1 = __hip_atomic_load(&g_Q1[c], __ATOMIC_RELAXED, __HIP_MEMORY_SCOPE_AGENT);
    __hip_atomic_store(&g_T0[c], 0ll, __ATOMIC_RELAXED, __HIP_MEMORY_SCOPE_AGENT);
    __hip_atomic_store(&g_T1[c], 0ll, __ATOMIC_RELAXED, __HIP_MEMORY_SCOPE_AGENT);
    __hip_atomic_store(&g_Q0[c], 0ll, __ATOMIC_RELAXED, __HIP_MEMORY_SCOPE_AGENT);
    __hip_atomic_store(&g_Q1[c], 0ll, __ATOMIC_RELAXED, __HIP_MEMORY_SCOPE_AGENT);
    const double M2 = 2.0 * (double)NPAIR;
    double s1 = (double)((long long)(NN-1)*T0 - T1) * (1.0/SL);
    double s2 = (double)T1 * (1.0/SL);
    double q1 = (double)((long long)(NN-1)*Q0 - Q1) * (1.0/SQ);
    double q2 = (double)Q1 * (1.0/SQ);
    double mu1 = s1/M2, mu2 = s2/M2;
    double v1 = q1/M2 - mu1*mu1;
    double v2 = q2/M2 - mu2*mu2;
    float m1 = (float)mu1, m2 = (float)mu2;
    float g1 = (float)((double)bn_g[c] / sqrt(v1 + 1e-5));
    float g2 = (float)((double)bn_g[HALF_FEAT+c] / sqrt(v2 + 1e-5));
    mu_out[c] = m1;  mu_out[HALF_FEAT+c] = m2;
    sg_out[c] = g1;  sg_out[HALF_FEAT+c] = g2;
    smu[c] = m1;  smu[HALF_FEAT+c] = m2;
    ssg[c] = g1;  ssg[HALF_FEAT+c] = g2;
  }
  if (lane == 0)
    __hip_atomic_store(&g_done, 0u, __ATOMIC_RELAXED, __HIP_MEMORY_SCOPE_AGENT);
  __syncthreads();
  if (lane < EMB) {
    float a0=0.f, a1=0.f, a2=0.f, a3=0.f;
    for (int c = 0; c < FEAT; c += 4) {
      a0 += (bn_b[c+0] - smu[c+0]*ssg[c+0]) * lin1_w[(c+0)*EMB + lane];
      a1 += (bn_b[c+1] - smu[c+1]*ssg[c+1]) * lin1_w[(c+1)*EMB + lane];
      a2 += (bn_b[c+2] - smu[c+2]*ssg[c+2]) * lin1_w[(c+2)*EMB + lane];
      a3 += (bn_b[c+3] - smu[c+3]*ssg[c+3]) * lin1_w[(c+3)*EMB + lane];
    }
    c0g[lane] = lin1_b[lane] + ((a0+a1)+(a2+a3));
  }
}

// ---------------- Kernel D: per-node u/v ----------------
__global__ void __launch_bounds__(64) uv_kernel(
    const float* __restrict__ feat0, const float* __restrict__ feat1,
    const float* __restrict__ e1, const float* __restrict__ e2,
    const float* __restrict__ sg,
    const float* __restrict__ lin1_w,
    float* __restrict__ u, float* __restrict__ v)
{
  const int i = blockIdx.x, g = blockIdx.y;
  const int t = threadIdx.x;
  __shared__ float x[HALF_FEAT];
  for (int c = t; c < IN_F; c += 64) x[c] = (g ? feat1 : feat0)[i*IN_F + c];
  if (t < 32) x[IN_F + t]     = e1[(g*NN+i)*EO + t];
  else        x[100 + (t-32)] = e2[(g*NN+i)*EO + (t-32)];
  __syncthreads();
  const int e = t & 31, hf = t >> 5;
  const int base = hf * HALF_FEAT;
  float a0=0.f, a1=0.f, a2=0.f, a3=0.f;
  for (int c = 0; c < HALF_FEAT; c += 4) {
    a0 += x[c+0] * sg[base+c+0] * lin1_w[(base+c+0)*EMB + e];
    a1 += x[c+1] * sg[base+c+1] * lin1_w[(base+c+1)*EMB + e];
    a2 += x[c+2] * sg[base+c+2] * lin1_w[(base+c+2)*EMB + e];
    a3 += x[c+3] * sg[base+c+3] * lin1_w[(base+c+3)*EMB + e];
  }
  float acc = ((a0+a1)+(a2+a3));
  float* dst = hf ? v : u;
  dst[(g*NN+i)*EMB + e] = acc;
}

// ---------------- Kernel E: pair MLP via split-bf16 MFMA (unchanged) ----------------
__global__ void __launch_bounds__(256) pair_kernel(
    const float* __restrict__ u, const float* __restrict__ v,
    const float* __restrict__ c0g,
    const float* __restrict__ lin2_w, const float* __restrict__ lin2_b,
    const float* __restrict__ lin3_w, const float* __restrict__ lin3_b,
    float2* __restrict__ out)
{
  const int g = blockIdx.y;
  int rem = blockIdx.x;        // 0..1175 triangular tile id
  int a = 0;
  while (rem >= 48 - a) { rem -= 48 - a; a++; }
  const int b = a + rem;

  __shared__ float su[16*36], sv[16*36];
  __shared__ float wbuf[4][16*36];
  const int tid = threadIdx.x;
  {
    int r = tid >> 5, c = tid & 31;
    su[r*36+c] = u[(g*NN + a*16 + r)*EMB + c];
    sv[r*36+c] = v[(g*NN + b*16 + r)*EMB + c];
    r += 8;
    su[r*36+c] = u[(g*NN + a*16 + r)*EMB + c];
    sv[r*36+c] = v[(g*NN + b*16 + r)*EMB + c];
  }
  __syncthreads();

  const int lane = tid & 63, w = tid >> 6;
  const int q = lane & 15, kg = lane >> 4;   // q: m/n index, kg: k-group

  union { int i[4]; bf16x8 v; } whi0, wlo0, whi1, wlo1;
#pragma unroll
  for (int d = 0; d < 4; d++) {
    float w0a = lin2_w[(kg*8+2*d)*32 + q];
    float w0b = lin2_w[(kg*8+2*d+1)*32 + q];
    float w1a = lin2_w[(kg*8+2*d)*32 + 16 + q];
    float w1b = lin2_w[(kg*8+2*d+1)*32 + 16 + q];
    whi0.i[d] = pack_chop2(w0a, w0b);
    wlo0.i[d] = pack_chop2(w0a - chop(w0a), w0b - chop(w0b));
    whi1.i[d] = pack_chop2(w1a, w1b);
    wlo1.i[d] = pack_chop2(w1a - chop(w1a), w1b - chop(w1b));
  }
  float svc[8];
#pragma unroll
  for (int jj = 0; jj < 8; jj++)
    svc[jj] = sv[q*36 + kg*8 + jj] + c0g[kg*8+jj];
  float2 w3v[8]; float b2v[8];
#pragma unroll
  for (int jj = 0; jj < 8; jj++) {
    w3v[jj] = ((const float2*)lin3_w)[kg*8+jj];
    b2v[jj] = lin2_b[kg*8+jj];
  }
  const float b30 = lin3_b[0], b31 = lin3_b[1];

  float* wb = wbuf[w];
#pragma unroll
  for (int t = 0; t < 4; t++) {
    const int ty = w*4 + t;
    const float4 sa = *(const float4*)&su[ty*36 + kg*8];
    const float4 sb = *(const float4*)&su[ty*36 + kg*8 + 4];
    float se[8] = {sa.x, sa.y, sa.z, sa.w, sb.x, sb.y, sb.z, sb.w};
    union { int i[4]; bf16x8 v; } ahi, alo;
#pragma unroll
    for (int d = 0; d < 4; d++) {
      float s0 = se[2*d]   + svc[2*d];
      float s1 = se[2*d+1] + svc[2*d+1];
      s0 = fmaxf(s0, 0.01f*s0);
      s1 = fmaxf(s1, 0.01f*s1);
      ahi.i[d] = pack_chop2(s0, s1);
      alo.i[d] = pack_chop2(s0 - chop(s0), s1 - chop(s1));
    }
    f32x4 acc0 = {0.f,0.f,0.f,0.f}, acc1 = {0.f,0.f,0.f,0.f};
    acc0 = __builtin_amdgcn_mfma_f32_16x16x32_bf16(ahi.v, whi0.v, acc0, 0,0,0);
    acc1 = __builtin_amdgcn_mfma_f32_16x16x32_bf16(ahi.v, whi1.v, acc1, 0,0,0);
    acc0 = __builtin_amdgcn_mfma_f32_16x16x32_bf16(ahi.v, wlo0.v, acc0, 0,0,0);
    acc1 = __builtin_amdgcn_mfma_f32_16x16x32_bf16(ahi.v, wlo1.v, acc1, 0,0,0);
    acc0 = __builtin_amdgcn_mfma_f32_16x16x32_bf16(alo.v, whi0.v, acc0, 0,0,0);
    acc1 = __builtin_amdgcn_mfma_f32_16x16x32_bf16(alo.v, whi1.v, acc1, 0,0,0);
#pragma unroll
    for (int r = 0; r < 4; r++) {
      wb[(kg*4+r)*36 + q]      = acc0[r];
      wb[(kg*4+r)*36 + 16 + q] = acc1[r];
    }
    float o0 = 0.f, o1 = 0.f;
#pragma unroll
    for (int jj = 0; jj < 8; jj++) {
      float h = wb[q*36 + kg*8 + jj] + b2v[jj];
      h = fmaxf(h, 0.01f*h);
      o0 += h * w3v[jj].x;
      o1 += h * w3v[jj].y;
    }
    o0 += __shfl_xor(o0, 16, 64); o0 += __shfl_xor(o0, 32, 64);
    o1 += __shfl_xor(o1, 16, 64); o1 += __shfl_xor(o1, 32, 64);
    const int i = a*16 + ty, j = b*16 + q;
    if (lane < 16 && j > i) {
      long p = (long)i*NN - (long)i*(i+1)/2 + (j - i - 1);
      out[(long)g*NPAIR + p] = make_float2(o0 + b30, o1 + b31);
    }
  }
}

extern "C" void kernel_launch(void* const* d_in, const int* in_sizes, int n_in,
                              void* d_out, int out_size, void* d_ws, size_t ws_size,
                              hipStream_t stream)
{
  const float* feat0  = (const float*)d_in[0];
  const float* feat1  = (const float*)d_in[1];
  const float* ec1_w1 = (const float*)d_in[2];
  const float* ec1_b1 = (const float*)d_in[3];
  const float* ec1_w2 = (const float*)d_in[4];
  const float* ec1_b2 = (const float*)d_in[5];
  const float* ec2_w1 = (const float*)d_in[6];
  const float* ec2_b1 = (const float*)d_in[7];
  const float* ec2_w2 = (const float*)d_in[8];
  const float* ec2_b2 = (const float*)d_in[9];
  const float* bn_g   = (const float*)d_in[10];
  const float* bn_b   = (const float*)d_in[11];
  const float* lin1_w = (const float*)d_in[12];
  const float* lin1_b = (const float*)d_in[13];
  const float* lin2_w = (const float*)d_in[14];
  const float* lin2_b = (const float*)d_in[15];
  const float* lin3_w = (const float*)d_in[16];
  const float* lin3_b = (const float*)d_in[17];

  char* ws = (char*)d_ws;
  int*   idx = (int*)  (ws + 0);
  float* e1  = (float*)(ws + 49152);
  float* e2  = (float*)(ws + 245760);
  float* u   = (float*)(ws + 442368);
  float* v   = (float*)(ws + 638976);
  float* mu  = (float*)(ws + 835584);
  float* sg  = (float*)(ws + 836640);
  float* c0g = (float*)(ws + 837696);

  topk_ec1_kernel<<<dim3(768,2), 64, 0, stream>>>(feat0, feat1, ec1_w1, ec1_b1,
                                                  ec1_w2, ec1_b2, idx, e1);
  ec2_kernel<<<dim3(768,2), 64, 0, stream>>>(idx, e1, ec2_w1, ec2_b1,
                                             ec2_w2, ec2_b2, bn_g, bn_b,
                                             lin1_w, lin1_b, e2, mu, sg, c0g);
  uv_kernel<<<dim3(768,2), 64, 0, stream>>>(feat0, feat1, e1, e2, sg,
                                            lin1_w, u, v);
  pair_kernel<<<dim3(1176,2), 256, 0, stream>>>(u, v, c0g, lin2_w, lin2_b,
                                                lin3_w, lin3_b, (float2*)d_out);
}

// Round 6
// 134.430 us; speedup vs baseline: 9.7665x; 1.7900x over previous
//
#include <hip/hip_runtime.h>

#define NN 768
#define IN_F 68
#define KNN 8
#define EO 32
#define FEAT 264
#define HALF_FEAT 132
#define EMB 32
#define NPAIR 294528   // 768*767/2

typedef __attribute__((ext_vector_type(8))) short bf16x8;
typedef __attribute__((ext_vector_type(4))) float f32x4;

// pack hi16(x1):hi16(x0) into one dword — bf16 truncation of two floats, 1 v_perm
static __device__ __forceinline__ int pack_chop2(float x0, float x1) {
  return __builtin_amdgcn_perm(__float_as_uint(x1), __float_as_uint(x0), 0x07060302);
}
static __device__ __forceinline__ float chop(float x) {
  return __uint_as_float(__float_as_uint(x) & 0xffff0000u);
}

// Session ledger (MI355X sync costs, measured r1-r4):
//   grid barrier (any impl): 230-400us @1538 blocks  -> never use
//   cross-XCD i64 atomics:   ~60us per ~600K RMWs    -> never bulk-use
//   kernel boundary:         ~10-15us                -> cheapest sync
// So: 5-kernel chain, shrink per-kernel latency instead.

// ---------------- Kernel A: top-8 neighbors + EdgeConv1 ----------------
// 128 threads / 2 waves per block (was 64/1): halves the serial candidate
// scan and the per-lane w1/w2 load chains, doubles waves/CU (6 -> 12) for
// latency hiding. Neighbor selection semantics identical to 64-thread
// version (unique keys (distbits<<32)|idx, global-min per round).
__global__ void __launch_bounds__(128) topk_ec1_kernel(
    const float* __restrict__ feat0, const float* __restrict__ feat1,
    const float* __restrict__ w1, const float* __restrict__ b1,
    const float* __restrict__ w2, const float* __restrict__ b2,
    int* __restrict__ idx_out, float* __restrict__ e1out)
{
  const int i = blockIdx.x, g = blockIdx.y;
  const float* __restrict__ feat = g ? feat1 : feat0;
  const int tid = threadIdx.x;
  const int lane = tid & 63, wv = tid >> 6;

  __shared__ unsigned long long keys[128*8];
  __shared__ int nbr[8];
  __shared__ float gl[KNN*IN_F];
  __shared__ float hsh[EO];
  __shared__ float part1[2][EO];
  __shared__ float part2[4][EO];

  const float4 ci = *(const float4*)(feat + i*IN_F);

  float4 cand[6];
#pragma unroll
  for (int t = 0; t < 6; t++)
    cand[t] = *(const float4*)(feat + (tid + 128*t)*IN_F);

  float bd[8]; int bidx[8];
#pragma unroll
  for (int k = 0; k < 8; k++) { bd[k] = 1e30f; bidx[k] = 0; }
#pragma unroll
  for (int t = 0; t < 6; t++) {
    const int j = tid + 128*t;
    float d = fabsf(ci.x - cand[t].x);   // same sequential add order as ref sum(-1)
    d += fabsf(ci.y - cand[t].y);
    d += fabsf(ci.z - cand[t].z);
    d += fabsf(ci.w - cand[t].w);
    if (d < bd[7]) {
#pragma unroll
      for (int k = 7; k >= 1; k--) {
        if (d < bd[k-1])    { bd[k] = bd[k-1]; bidx[k] = bidx[k-1]; }
        else if (d < bd[k]) { bd[k] = d;       bidx[k] = j; }
      }
      if (d < bd[0]) { bd[0] = d; bidx[0] = j; }
    }
  }
#pragma unroll
  for (int k = 0; k < 8; k++)
    keys[tid*8+k] = ((unsigned long long)__float_as_uint(bd[k]) << 32) | (unsigned)bidx[k];
  __syncthreads();

  // wave 0 merges 128 sorted lists: each lane tracks 2 list heads.
  // All real keys are unique ((distbits<<32)|idx); sentinels (1e30,0) can
  // never be a round's global min (768 real candidates > 8 rounds).
  if (wv == 0) {
    int posA = 0, posB = 0;
#pragma unroll
    for (int r = 0; r < 8; r++) {
      unsigned long long ha = keys[lane*8 + posA];
      unsigned long long hb = keys[(lane+64)*8 + posB];
      unsigned long long mn = ha < hb ? ha : hb;
#pragma unroll
      for (int s = 32; s >= 1; s >>= 1) {
        unsigned long long o = __shfl_xor(mn, s, 64);
        mn = (o < mn) ? o : mn;
      }
      if (ha == mn) posA++;
      else if (hb == mn) posB++;
      if (lane == 0) {
        int nb = (int)(mn & 0xffffffffull);
        nbr[r] = nb;
        idx_out[(g*NN+i)*8 + r] = nb;
      }
    }
  }
  __syncthreads();

  for (int z = tid; z < KNN*17; z += 128) {
    int k = z / 17, q = z - k*17;
    *(float4*)&gl[k*IN_F + q*4] = *(const float4*)(feat + nbr[k]*IN_F + q*4);
  }
  __syncthreads();

  // layer1: wave wv owns k-chains {4wv..4wv+3}; half-wave hf owns c-chunk.
  const int e = lane & 31, hf = lane >> 5;
  float ak[4];
#pragma unroll
  for (int k = 0; k < 4; k++) ak[k] = 0.f;
  const int cbeg = hf*34;
  const int kbase = wv*4;
  for (int c = cbeg; c < cbeg+34; c++) {
#pragma unroll
    for (int k = 0; k < 4; k++)
      ak[k] += gl[(kbase+k)*IN_F+c] * w1[(c*8+kbase+k)*EO + e];
  }
  float acc = (ak[0]+ak[1])+(ak[2]+ak[3]);
  acc += __shfl_xor(acc, 32, 64);
  if (hf == 0) part1[wv][e] = acc;
  __syncthreads();
  if (tid < 32) {
    float h = part1[0][tid] + part1[1][tid] + b1[tid];
    hsh[tid] = fmaxf(h, 0.01f*h);
  }
  __syncthreads();

  // layer2: quarter qq owns m-range [8qq, 8qq+8).
  const int qq = tid >> 5, ee = tid & 31;
  {
    float o0=0.f, o1=0.f, o2=0.f, o3=0.f;
    const int mbeg = qq*8;
#pragma unroll
    for (int m = mbeg; m < mbeg+8; m += 4) {
      o0 += hsh[m+0] * w2[(m+0)*EO + ee];
      o1 += hsh[m+1] * w2[(m+1)*EO + ee];
      o2 += hsh[m+2] * w2[(m+2)*EO + ee];
      o3 += hsh[m+3] * w2[(m+3)*EO + ee];
    }
    part2[qq][ee] = ((o0+o1)+(o2+o3));
  }
  __syncthreads();
  if (tid < 32) {
    float o = b2[tid] + ((part2[0][tid]+part2[1][tid])+(part2[2][tid]+part2[3][tid]));
    o = fmaxf(o, 0.01f*o);
    e1out[(g*NN+i)*EO + tid] = o;
  }
}

// ---------------- Kernel B: EdgeConv2 ----------------
__global__ void __launch_bounds__(64) ec2_kernel(
    const int* __restrict__ idx, const float* __restrict__ e1,
    const float* __restrict__ w1, const float* __restrict__ b1,
    const float* __restrict__ w2, const float* __restrict__ b2,
    float* __restrict__ e2out)
{
  const int i = blockIdx.x, g = blockIdx.y;
  const int lane = threadIdx.x;
  __shared__ float gl[KNN*EO];
  __shared__ float hsh[EO];
  {
    const int k = lane >> 3, q = lane & 7;
    const int nb = idx[(g*NN+i)*8 + k];
    *(float4*)&gl[k*EO + q*4] = *(const float4*)(e1 + (g*NN+nb)*EO + q*4);
  }
  __syncthreads();
  const int e = lane & 31, hf = lane >> 5;
  float ak[8];
#pragma unroll
  for (int k = 0; k < 8; k++) ak[k] = 0.f;
  const int cbeg = hf*16;
  for (int c = cbeg; c < cbeg+16; c++) {
#pragma unroll
    for (int k = 0; k < 8; k++)
      ak[k] += gl[k*EO+c] * w1[(c*8+k)*EO + e];
  }
  float acc = ((ak[0]+ak[1])+(ak[2]+ak[3])) + ((ak[4]+ak[5])+(ak[6]+ak[7]));
  acc += __shfl_xor(acc, 32, 64);
  if (hf == 0) {
    float h = acc + b1[e];
    hsh[e] = fmaxf(h, 0.01f*h);
  }
  __syncthreads();
  if (lane < 32) {
    float o0=0.f, o1=0.f, o2=0.f, o3=0.f;
#pragma unroll
    for (int m = 0; m < 32; m += 4) {
      o0 += hsh[m+0] * w2[(m+0)*EO + lane];
      o1 += hsh[m+1] * w2[(m+1)*EO + lane];
      o2 += hsh[m+2] * w2[(m+2)*EO + lane];
      o3 += hsh[m+3] * w2[(m+3)*EO + lane];
    }
    float o = b2[lane] + ((o0+o1)+(o2+o3));
    o = fmaxf(o, 0.01f*o);
    e2out[(g*NN+i)*EO + lane] = o;
  }
}

// ---------------- Kernel C: BN stats (weighted node sums, shfl reduce) ----------------
__global__ void __launch_bounds__(256) stats_kernel(
    const float* __restrict__ feat0, const float* __restrict__ feat1,
    const float* __restrict__ e1, const float* __restrict__ e2,
    const float* __restrict__ bn_g,
    float* __restrict__ mu_out, float* __restrict__ sg_out)
{
  const int c = blockIdx.x;   // 0..131
  const int tid = threadIdx.x;
  double s1=0, s2=0, q1=0, q2=0;
  for (int t = tid; t < 2*NN; t += 256) {
    int g = t >= NN;
    int i = t - g*NN;
    float val;
    if (c < IN_F)      val = (g ? feat1 : feat0)[i*IN_F + c];
    else if (c < 100)  val = e1[(g*NN+i)*EO + (c-IN_F)];
    else               val = e2[(g*NN+i)*EO + (c-100)];
    double dv = val;
    double wf = (double)(NN-1-i), wsnd = (double)i;
    s1 += wf*dv;  s2 += wsnd*dv;
    double dq = dv*dv;
    q1 += wf*dq;  q2 += wsnd*dq;
  }
#pragma unroll
  for (int off = 32; off >= 1; off >>= 1) {
    s1 += __shfl_xor(s1, off, 64);
    s2 += __shfl_xor(s2, off, 64);
    q1 += __shfl_xor(q1, off, 64);
    q2 += __shfl_xor(q2, off, 64);
  }
  __shared__ double red[4][4];
  const int w = tid >> 6;
  if ((tid & 63) == 0) { red[w][0]=s1; red[w][1]=s2; red[w][2]=q1; red[w][3]=q2; }
  __syncthreads();
  if (tid == 0) {
    double t0 = red[0][0]+red[1][0]+red[2][0]+red[3][0];
    double t1 = red[0][1]+red[1][1]+red[2][1]+red[3][1];
    double t2 = red[0][2]+red[1][2]+red[2][2]+red[3][2];
    double t3 = red[0][3]+red[1][3]+red[2][3]+red[3][3];
    const double M2 = 2.0 * (double)NPAIR;
    double mu1 = t0/M2, mu2 = t1/M2;
    double v1 = t2/M2 - mu1*mu1;
    double v2 = t3/M2 - mu2*mu2;
    mu_out[c]           = (float)mu1;
    mu_out[HALF_FEAT+c] = (float)mu2;
    sg_out[c]           = (float)((double)bn_g[c] / sqrt(v1 + 1e-5));
    sg_out[HALF_FEAT+c] = (float)((double)bn_g[HALF_FEAT+c] / sqrt(v2 + 1e-5));
  }
}

// ---------------- Kernel D: per-node u/v, plus c0 ----------------
__global__ void __launch_bounds__(64) uv_c0_kernel(
    const float* __restrict__ feat0, const float* __restrict__ feat1,
    const float* __restrict__ e1, const float* __restrict__ e2,
    const float* __restrict__ sg, const float* __restrict__ mu,
    const float* __restrict__ bn_b,
    const float* __restrict__ lin1_w, const float* __restrict__ lin1_b,
    float* __restrict__ u, float* __restrict__ v, float* __restrict__ c0g)
{
  const int i = blockIdx.x, g = blockIdx.y;
  const int t = threadIdx.x;
  if (i == NN) {
    if (g == 0 && t < EMB) {
      float a0=0.f, a1=0.f, a2=0.f, a3=0.f;
      for (int c = 0; c < FEAT; c += 4) {
        a0 += (bn_b[c+0] - mu[c+0]*sg[c+0]) * lin1_w[(c+0)*EMB + t];
        a1 += (bn_b[c+1] - mu[c+1]*sg[c+1]) * lin1_w[(c+1)*EMB + t];
        a2 += (bn_b[c+2] - mu[c+2]*sg[c+2]) * lin1_w[(c+2)*EMB + t];
        a3 += (bn_b[c+3] - mu[c+3]*sg[c+3]) * lin1_w[(c+3)*EMB + t];
      }
      c0g[t] = lin1_b[t] + ((a0+a1)+(a2+a3));
    }
    return;
  }
  __shared__ float x[HALF_FEAT];
  for (int c = t; c < IN_F; c += 64) x[c] = (g ? feat1 : feat0)[i*IN_F + c];
  if (t < 32) x[IN_F + t]     = e1[(g*NN+i)*EO + t];
  else        x[100 + (t-32)] = e2[(g*NN+i)*EO + (t-32)];
  __syncthreads();
  const int e = t & 31, hf = t >> 5;
  const int base = hf * HALF_FEAT;
  float a0=0.f, a1=0.f, a2=0.f, a3=0.f;
  for (int c = 0; c < HALF_FEAT; c += 4) {
    a0 += x[c+0] * sg[base+c+0] * lin1_w[(base+c+0)*EMB + e];
    a1 += x[c+1] * sg[base+c+1] * lin1_w[(base+c+1)*EMB + e];
    a2 += x[c+2] * sg[base+c+2] * lin1_w[(base+c+2)*EMB + e];
    a3 += x[c+3] * sg[base+c+3] * lin1_w[(base+c+3)*EMB + e];
  }
  float acc = ((a0+a1)+(a2+a3));
  float* dst = hf ? v : u;
  dst[(g*NN+i)*EMB + e] = acc;
}

// ---------------- Kernel E: pair MLP via split-bf16 MFMA ----------------
__global__ void __launch_bounds__(256) pair_kernel(
    const float* __restrict__ u, const float* __restrict__ v,
    const float* __restrict__ c0g,
    const float* __restrict__ lin2_w, const float* __restrict__ lin2_b,
    const float* __restrict__ lin3_w, const float* __restrict__ lin3_b,
    float2* __restrict__ out)
{
  const int g = blockIdx.y;
  int rem = blockIdx.x;        // 0..1175 triangular tile id
  int a = 0;
  while (rem >= 48 - a) { rem -= 48 - a; a++; }
  const int b = a + rem;

  __shared__ float su[16*36], sv[16*36];
  __shared__ float wbuf[4][16*36];
  const int tid = threadIdx.x;
  {
    int r = tid >> 5, c = tid & 31;
    su[r*36+c] = u[(g*NN + a*16 + r)*EMB + c];
    sv[r*36+c] = v[(g*NN + b*16 + r)*EMB + c];
    r += 8;
    su[r*36+c] = u[(g*NN + a*16 + r)*EMB + c];
    sv[r*36+c] = v[(g*NN + b*16 + r)*EMB + c];
  }
  __syncthreads();

  const int lane = tid & 63, w = tid >> 6;
  const int q = lane & 15, kg = lane >> 4;   // q: m/n index, kg: k-group

  union { int i[4]; bf16x8 v; } whi0, wlo0, whi1, wlo1;
#pragma unroll
  for (int d = 0; d < 4; d++) {
    float w0a = lin2_w[(kg*8+2*d)*32 + q];
    float w0b = lin2_w[(kg*8+2*d+1)*32 + q];
    float w1a = lin2_w[(kg*8+2*d)*32 + 16 + q];
    float w1b = lin2_w[(kg*8+2*d+1)*32 + 16 + q];
    whi0.i[d] = pack_chop2(w0a, w0b);
    wlo0.i[d] = pack_chop2(w0a - chop(w0a), w0b - chop(w0b));
    whi1.i[d] = pack_chop2(w1a, w1b);
    wlo1.i[d] = pack_chop2(w1a - chop(w1a), w1b - chop(w1b));
  }
  float svc[8];
#pragma unroll
  for (int jj = 0; jj < 8; jj++)
    svc[jj] = sv[q*36 + kg*8 + jj] + c0g[kg*8+jj];
  float2 w3v[8]; float b2v[8];
#pragma unroll
  for (int jj = 0; jj < 8; jj++) {
    w3v[jj] = ((const float2*)lin3_w)[kg*8+jj];
    b2v[jj] = lin2_b[kg*8+jj];
  }
  const float b30 = lin3_b[0], b31 = lin3_b[1];

  float* wb = wbuf[w];
#pragma unroll
  for (int t = 0; t < 4; t++) {
    const int ty = w*4 + t;
    const float4 sa = *(const float4*)&su[ty*36 + kg*8];
    const float4 sb = *(const float4*)&su[ty*36 + kg*8 + 4];
    float se[8] = {sa.x, sa.y, sa.z, sa.w, sb.x, sb.y, sb.z, sb.w};
    union { int i[4]; bf16x8 v; } ahi, alo;
#pragma unroll
    for (int d = 0; d < 4; d++) {
      float s0 = se[2*d]   + svc[2*d];
      float s1 = se[2*d+1] + svc[2*d+1];
      s0 = fmaxf(s0, 0.01f*s0);
      s1 = fmaxf(s1, 0.01f*s1);
      ahi.i[d] = pack_chop2(s0, s1);
      alo.i[d] = pack_chop2(s0 - chop(s0), s1 - chop(s1));
    }
    f32x4 acc0 = {0.f,0.f,0.f,0.f}, acc1 = {0.f,0.f,0.f,0.f};
    acc0 = __builtin_amdgcn_mfma_f32_16x16x32_bf16(ahi.v, whi0.v, acc0, 0,0,0);
    acc1 = __builtin_amdgcn_mfma_f32_16x16x32_bf16(ahi.v, whi1.v, acc1, 0,0,0);
    acc0 = __builtin_amdgcn_mfma_f32_16x16x32_bf16(ahi.v, wlo0.v, acc0, 0,0,0);
    acc1 = __builtin_amdgcn_mfma_f32_16x16x32_bf16(ahi.v, wlo1.v, acc1, 0,0,0);
    acc0 = __builtin_amdgcn_mfma_f32_16x16x32_bf16(alo.v, whi0.v, acc0, 0,0,0);
    acc1 = __builtin_amdgcn_mfma_f32_16x16x32_bf16(alo.v, whi1.v, acc1, 0,0,0);
#pragma unroll
    for (int r = 0; r < 4; r++) {
      wb[(kg*4+r)*36 + q]      = acc0[r];
      wb[(kg*4+r)*36 + 16 + q] = acc1[r];
    }
    float o0 = 0.f, o1 = 0.f;
#pragma unroll
    for (int jj = 0; jj < 8; jj++) {
      float h = wb[q*36 + kg*8 + jj] + b2v[jj];
      h = fmaxf(h, 0.01f*h);
      o0 += h * w3v[jj].x;
      o1 += h * w3v[jj].y;
    }
    o0 += __shfl_xor(o0, 16, 64); o0 += __shfl_xor(o0, 32, 64);
    o1 += __shfl_xor(o1, 16, 64); o1 += __shfl_xor(o1, 32, 64);
    const int i = a*16 + ty, j = b*16 + q;
    if (lane < 16 && j > i) {
      long p = (long)i*NN - (long)i*(i+1)/2 + (j - i - 1);
      out[(long)g*NPAIR + p] = make_float2(o0 + b30, o1 + b31);
    }
  }
}

extern "C" void kernel_launch(void* const* d_in, const int* in_sizes, int n_in,
                              void* d_out, int out_size, void* d_ws, size_t ws_size,
                              hipStream_t stream)
{
  const float* feat0  = (const float*)d_in[0];
  const float* feat1  = (const float*)d_in[1];
  const float* ec1_w1 = (const float*)d_in[2];
  const float* ec1_b1 = (const float*)d_in[3];
  const float* ec1_w2 = (const float*)d_in[4];
  const float* ec1_b2 = (const float*)d_in[5];
  const float* ec2_w1 = (const float*)d_in[6];
  const float* ec2_b1 = (const float*)d_in[7];
  const float* ec2_w2 = (const float*)d_in[8];
  const float* ec2_b2 = (const float*)d_in[9];
  const float* bn_g   = (const float*)d_in[10];
  const float* bn_b   = (const float*)d_in[11];
  const float* lin1_w = (const float*)d_in[12];
  const float* lin1_b = (const float*)d_in[13];
  const float* lin2_w = (const float*)d_in[14];
  const float* lin2_b = (const float*)d_in[15];
  const float* lin3_w = (const float*)d_in[16];
  const float* lin3_b = (const float*)d_in[17];

  char* ws = (char*)d_ws;
  int*   idx = (int*)  (ws + 0);
  float* e1  = (float*)(ws + 49152);
  float* e2  = (float*)(ws + 245760);
  float* u   = (float*)(ws + 442368);
  float* v   = (float*)(ws + 638976);
  float* mu  = (float*)(ws + 835584);
  float* sg  = (float*)(ws + 836640);
  float* c0g = (float*)(ws + 837696);

  topk_ec1_kernel<<<dim3(768,2), 128, 0, stream>>>(feat0, feat1, ec1_w1, ec1_b1,
                                                   ec1_w2, ec1_b2, idx, e1);
  ec2_kernel<<<dim3(768,2), 64, 0, stream>>>(idx, e1, ec2_w1, ec2_b1,
                                             ec2_w2, ec2_b2, e2);
  stats_kernel<<<dim3(132), 256, 0, stream>>>(feat0, feat1, e1, e2, bn_g, mu, sg);
  uv_c0_kernel<<<dim3(769,2), 64, 0, stream>>>(feat0, feat1, e1, e2, sg, mu, bn_b,
                                               lin1_w, lin1_b, u, v, c0g);
  pair_kernel<<<dim3(1176,2), 256, 0, stream>>>(u, v, c0g, lin2_w, lin2_b,
                                                lin3_w, lin3_b, (float2*)d_out);
}